// Round 2
// baseline (1021.674 us; speedup 1.0000x reference)
//
#include <hip/hip_runtime.h>

// Correlation3D: pm = box3(mov, pad1); pf = box3(fix, pad3) [100^3];
// out[d=(i,j,k), x,y,z] = (1/27) * sum_c pm[c,x,y,z] * pf[c, x+2i, y+2j, z+2k]
//
// Stage 1 writes pf (32*100^3 f32 = 128 MB) into d_ws.
// Stage 2 recomputes pm (bm) in registers and correlates against pf.

#define CCH 32
#define HH  96
#define PP  100

// ---------------- Stage 1: padded box filter of fix -> pf ----------------
// pf[c][ox][oy][oz] = sum_{a,b,m in {0,1,2}^3} fix[c][ox-3+a][oy-3+b][oz-3+m]
// (zero outside [0,96)). Thread computes 4 consecutive oz.
__global__ __launch_bounds__(256) void pf_kernel(const float* __restrict__ fix,
                                                 float* __restrict__ pf) {
    int t = blockIdx.x * 256 + threadIdx.x;   // total = 32*100*100*25
    int qz = t % 25;
    int r  = t / 25;
    int oy = r % 100;
    r /= 100;
    int ox = r % 100;
    int c  = r / 100;
    int oz0 = qz * 4;

    // source z indices: sz = oz0-3+m, m=0..5 ; clamp + float mask (branchless)
    int   szc[6];
    float zm[6];
#pragma unroll
    for (int m = 0; m < 6; ++m) {
        int s = oz0 - 3 + m;
        zm[m]  = (s >= 0 && s < HH) ? 1.0f : 0.0f;
        szc[m] = min(max(s, 0), HH - 1);
    }

    float tt[6] = {0.f, 0.f, 0.f, 0.f, 0.f, 0.f};
#pragma unroll
    for (int a = 0; a < 3; ++a) {
        int sx = ox - 3 + a;
        if ((unsigned)sx >= (unsigned)HH) continue;
#pragma unroll
        for (int b = 0; b < 3; ++b) {
            int sy = oy - 3 + b;
            if ((unsigned)sy >= (unsigned)HH) continue;
            const float* row = fix + ((size_t)((c * HH + sx) * HH + sy)) * HH;
#pragma unroll
            for (int m = 0; m < 6; ++m)
                tt[m] = fmaf(row[szc[m]], zm[m], tt[m]);
        }
    }

    float4 o;
    o.x = tt[0] + tt[1] + tt[2];
    o.y = tt[1] + tt[2] + tt[3];
    o.z = tt[2] + tt[3] + tt[4];
    o.w = tt[3] + tt[4] + tt[5];
    *(float4*)(pf + ((size_t)((c * PP + ox) * PP + oy)) * PP + oz0) = o;
}

// ---------------- Stage 2: correlate bm(mov) x pf ----------------
// Thread handles 4 consecutive z voxels, all 27 displacements, loops channels.
__global__ __launch_bounds__(256) void corr_kernel(const float* __restrict__ mov,
                                                   const float* __restrict__ pf,
                                                   float* __restrict__ out) {
    int t = blockIdx.x * 256 + threadIdx.x;   // total = 96*96*24
    int qz = t % 24;
    int r  = t / 24;
    int y  = r % 96;
    int x  = r / 96;
    int z0 = qz * 4;

    // mov source z: sz = z0-1+m, m=0..5 ; clamp + mask
    int   szc[6];
    float zm[6];
#pragma unroll
    for (int m = 0; m < 6; ++m) {
        int s = z0 - 1 + m;
        zm[m]  = (s >= 0 && s < HH) ? 1.0f : 0.0f;
        szc[m] = min(max(s, 0), HH - 1);
    }

    float acc[27][4];
#pragma unroll
    for (int d = 0; d < 27; ++d)
#pragma unroll
        for (int q = 0; q < 4; ++q) acc[d][q] = 0.f;

    for (int c = 0; c < CCH; ++c) {
        // z-partial sums of the 3x3 xy-neighborhood of mov
        float tt[6] = {0.f, 0.f, 0.f, 0.f, 0.f, 0.f};
#pragma unroll
        for (int a = 0; a < 3; ++a) {
            int sx = x + a - 1;
            if ((unsigned)sx >= (unsigned)HH) continue;
#pragma unroll
            for (int b = 0; b < 3; ++b) {
                int sy = y + b - 1;
                if ((unsigned)sy >= (unsigned)HH) continue;
                const float* row = mov + ((size_t)((c * HH + sx) * HH + sy)) * HH;
#pragma unroll
                for (int m = 0; m < 6; ++m)
                    tt[m] = fmaf(row[szc[m]], zm[m], tt[m]);
            }
        }
        float bm[4];
#pragma unroll
        for (int q = 0; q < 4; ++q) bm[q] = tt[q] + tt[q + 1] + tt[q + 2];

        // correlation: for each (i,j), 8 consecutive pf z-values serve all 3 k
#pragma unroll
        for (int i = 0; i < 3; ++i) {
            int px = x + 2 * i;
#pragma unroll
            for (int j = 0; j < 3; ++j) {
                int py = y + 2 * j;
                const float* prow =
                    pf + ((size_t)((c * PP + px) * PP + py)) * PP + z0;
                float4 w0 = *(const float4*)(prow);
                float4 w1 = *(const float4*)(prow + 4);
                float w[8] = {w0.x, w0.y, w0.z, w0.w, w1.x, w1.y, w1.z, w1.w};
#pragma unroll
                for (int k = 0; k < 3; ++k) {
                    int d = i * 9 + j * 3 + k;
#pragma unroll
                    for (int q = 0; q < 4; ++q)
                        acc[d][q] = fmaf(bm[q], w[q + 2 * k], acc[d][q]);
                }
            }
        }
    }

    const float s = 1.0f / 27.0f;
#pragma unroll
    for (int d = 0; d < 27; ++d) {
        float4 o;
        o.x = acc[d][0] * s;
        o.y = acc[d][1] * s;
        o.z = acc[d][2] * s;
        o.w = acc[d][3] * s;
        *(float4*)(out + ((size_t)((d * HH + x) * HH + y)) * HH + z0) = o;
    }
}

extern "C" void kernel_launch(void* const* d_in, const int* in_sizes, int n_in,
                              void* d_out, int out_size, void* d_ws, size_t ws_size,
                              hipStream_t stream) {
    const float* mov = (const float*)d_in[0];
    const float* fix = (const float*)d_in[1];
    float* out = (float*)d_out;
    float* pf  = (float*)d_ws;

    // pf needs 32*100*100*100*4 = 128,000,000 bytes of workspace.
    if (ws_size < (size_t)CCH * PP * PP * PP * sizeof(float)) {
        // Insufficient workspace: fail loudly (output stays zero) rather than
        // corrupt memory beyond the workspace.
        return;
    }

    // Stage 1: 32*100*100*25 = 8,000,000 threads -> 31250 blocks of 256
    pf_kernel<<<31250, 256, 0, stream>>>(fix, pf);

    // Stage 2: 96*96*24 = 221,184 threads -> 864 blocks of 256
    corr_kernel<<<864, 256, 0, stream>>>(mov, pf, out);
}

// Round 5
// 771.239 us; speedup vs baseline: 1.3247x; 1.3247x over previous
//
#include <hip/hip_runtime.h>

// Correlation3D: pm = box3(mov, pad1); pf = box3(fix, pad3) [100^3];
// out[d=(i,j,k), x,y,z] = (1/27) * sum_c pm[c,x,y,z] * pf[c, x+2i, y+2j, z+2k]
//
// Stage 1 (pf1): scalar, z-lane-coalesced box filter of fix -> pf in d_ws.
// Stage 2 (corr2): LDS-tiled; block = (x, 8-y tile, all z); per channel stage
// mov/pf slabs in LDS, read fragments as ds_read_b64 (2-way = free).

#define CCH 32
#define HH  96
#define PP  100
#define TY  8            // y-tile per block
#define NZP 48           // z-pairs per block (96 z)
#define TPB (NZP * TY)   // 384 threads
#define MST 104          // slab z-stride (floats): 8/16B aligned, +8 bank shift/row

// ---------------- Stage 1: padded box filter of fix -> pf ----------------
// One thread per pf voxel; lanes contiguous along oz (coalesced 4B loads).
__global__ __launch_bounds__(256) void pf1(const float* __restrict__ fix,
                                           float* __restrict__ pf) {
    int t = blockIdx.x * 256 + threadIdx.x;   // total = 32*100*100*100
    int oz = t % PP;
    int r  = t / PP;
    int oy = r % PP;
    r /= PP;
    int ox = r % PP;
    int c  = r / PP;

    // z window: sz = oz-3+m, m=0..2 ; clamp + float mask (branchless)
    int   szc[3];
    float zm[3];
#pragma unroll
    for (int m = 0; m < 3; ++m) {
        int s = oz - 3 + m;
        zm[m]  = ((unsigned)s < (unsigned)HH) ? 1.0f : 0.0f;
        szc[m] = min(max(s, 0), HH - 1);
    }

    float acc = 0.f;
#pragma unroll
    for (int a = 0; a < 3; ++a) {
        int sx = ox - 3 + a;
        if ((unsigned)sx >= (unsigned)HH) continue;
#pragma unroll
        for (int b = 0; b < 3; ++b) {
            int sy = oy - 3 + b;
            if ((unsigned)sy >= (unsigned)HH) continue;
            const float* row = fix + ((size_t)((c * HH + sx) * HH + sy)) * HH;
#pragma unroll
            for (int m = 0; m < 3; ++m)
                acc = fmaf(row[szc[m]], zm[m], acc);
        }
    }
    pf[((size_t)((c * PP + ox) * PP + oy)) * PP + oz] = acc;
}

// ---------------- Stage 2: LDS-tiled correlation ----------------
__global__ __launch_bounds__(TPB) void corr2(const float* __restrict__ mov,
                                             const float* __restrict__ pf,
                                             float* __restrict__ out) {
    // mov slab: rows (a in 0..2) x (r in 0..TY+1), sy = y0-1+r; z stored at zi=z+4
    __shared__ float ms[3 * (TY + 2) * MST];
    // pf slab: rows (i in 0..2) x (r in 0..TY+3), py = y0+r; z stored at zi=oz
    __shared__ float ps[3 * (TY + 4) * MST];

    const int tid = threadIdx.x;
    const int zp  = tid % NZP;         // 0..47
    const int yy  = tid / NZP;         // 0..7
    const int bx  = blockIdx.x;        // 0..95
    const int y0  = blockIdx.y * TY;   // 0..88
    const int z0  = zp * 2;

    // Pre-zero mov slab once: z-pads + OOB rows stay zero forever.
    for (int s = tid; s < 3 * (TY + 2) * MST; s += TPB) ms[s] = 0.f;

    float acc[27][2];
#pragma unroll
    for (int d = 0; d < 27; ++d) { acc[d][0] = 0.f; acc[d][1] = 0.f; }

    const int NMS = 3 * (TY + 2) * (HH / 4);   // 720 mov float4 slots
    const int NPS = 3 * (TY + 4) * (PP / 4);   // 900 pf  float4 slots

    for (int c = 0; c < CCH; ++c) {
        __syncthreads();   // previous compute done (and initial pre-zero)
        for (int s = tid; s < NMS + NPS; s += TPB) {
            if (s < NMS) {
                int q = s % (HH / 4);
                int r = (s / (HH / 4)) % (TY + 2);
                int a = s / ((HH / 4) * (TY + 2));
                int sx = bx - 1 + a, sy = y0 - 1 + r;
                if ((unsigned)sx < (unsigned)HH && (unsigned)sy < (unsigned)HH) {
                    float4 v = *(const float4*)(
                        mov + ((size_t)((c * HH + sx) * HH + sy)) * HH + 4 * q);
                    *(float4*)(ms + (a * (TY + 2) + r) * MST + 4 + 4 * q) = v;
                }
            } else {
                int s2 = s - NMS;
                int q = s2 % (PP / 4);
                int r = (s2 / (PP / 4)) % (TY + 4);
                int i = s2 / ((PP / 4) * (TY + 4));
                int px = bx + 2 * i, py = y0 + r;   // always in-bounds
                float4 v = *(const float4*)(
                    pf + ((size_t)((c * PP + px) * PP + py)) * PP + 4 * q);
                *(float4*)(ps + (i * (TY + 4) + r) * MST + 4 * q) = v;
            }
        }
        __syncthreads();

        // bm for the two z outputs (z0, z0+1): sum of 9 zero-padded columns
        float b0 = 0.f, b1 = 0.f;
#pragma unroll
        for (int a = 0; a < 3; ++a)
#pragma unroll
            for (int b = 0; b < 3; ++b) {
                const float* col = ms + (a * (TY + 2) + (yy + b)) * MST + (z0 + 2);
                // zi z0+2..z0+7 == mov z (z0-2..z0+3), pads are zero
                float2 u0 = *(const float2*)(col);       // v0 v1
                float2 u1 = *(const float2*)(col + 2);   // v2 v3
                float2 u2 = *(const float2*)(col + 4);   // v4 v5
                b0 += u0.y + u1.x + u1.y;   // z0-1, z0, z0+1
                b1 += u1.x + u1.y + u2.x;   // z0,   z0+1, z0+2
            }

        // 27 taps: pf[bx+2i][y0+yy+2j][z0+2k (+1)]
#pragma unroll
        for (int i = 0; i < 3; ++i)
#pragma unroll
            for (int j = 0; j < 3; ++j) {
                const float* col = ps + (i * (TY + 4) + (yy + 2 * j)) * MST + z0;
                float2 w0 = *(const float2*)(col);
                float2 w1 = *(const float2*)(col + 2);
                float2 w2 = *(const float2*)(col + 4);
                int d = i * 9 + j * 3;
                acc[d][0]     = fmaf(b0, w0.x, acc[d][0]);
                acc[d][1]     = fmaf(b1, w0.y, acc[d][1]);
                acc[d + 1][0] = fmaf(b0, w1.x, acc[d + 1][0]);
                acc[d + 1][1] = fmaf(b1, w1.y, acc[d + 1][1]);
                acc[d + 2][0] = fmaf(b0, w2.x, acc[d + 2][0]);
                acc[d + 2][1] = fmaf(b1, w2.y, acc[d + 2][1]);
            }
    }

    const float sc = 1.0f / 27.0f;
    const int yo = y0 + yy;
#pragma unroll
    for (int d = 0; d < 27; ++d) {
        float2 o;
        o.x = acc[d][0] * sc;
        o.y = acc[d][1] * sc;
        *(float2*)(out + ((size_t)((d * HH + bx) * HH + yo)) * HH + z0) = o;
    }
}

extern "C" void kernel_launch(void* const* d_in, const int* in_sizes, int n_in,
                              void* d_out, int out_size, void* d_ws, size_t ws_size,
                              hipStream_t stream) {
    const float* mov = (const float*)d_in[0];
    const float* fix = (const float*)d_in[1];
    float* out = (float*)d_out;
    float* pf  = (float*)d_ws;

    // pf needs 32*100^3*4 = 128,000,000 bytes of workspace.
    if (ws_size < (size_t)CCH * PP * PP * PP * sizeof(float)) return;

    // Stage 1: 32*100^3 = 32,000,000 threads -> 125000 blocks of 256
    pf1<<<125000, 256, 0, stream>>>(fix, pf);

    // Stage 2: grid (x=96, ygrp=12), 384 threads
    corr2<<<dim3(96, 12), TPB, 0, stream>>>(mov, pf, out);
}

// Round 6
// 618.171 us; speedup vs baseline: 1.6527x; 1.2476x over previous
//
#include <hip/hip_runtime.h>

// Correlation3D: pm = box3(mov, pad1); pf = box3(fix, pad3) [100^3];
// out[d=(i,j,k), x,y,z] = (1/27) * sum_c pm[c,x,y,z] * pf[c, x+2i, y+2j, z+2k]
//
// pf2:   thread = float4 of pf outputs along z, direct from global (no LDS).
// corr3: block = (x, 8-y, all z), 4 z/thread; LDS: x-presummed mov slab (xs)
//        + pf slab (ps); taps are aligned ds_read_b128 (2 FMA/dword).

#define CCH 32
#define HH  96
#define PP  100
#define TY  8              // y-tile per block
#define NZQ 24             // z-quads per block (96 z / 4)
#define TPB (NZQ * TY)     // 192 threads
#define MST 104            // slab z-stride (floats), 16B-aligned rows

// ---------------- Stage 1: padded box filter of fix -> pf ----------------
// One thread per float4 of pf outputs [oz0..oz0+3].
__global__ __launch_bounds__(256) void pf2(const float* __restrict__ fix,
                                           float* __restrict__ pf) {
    int t = blockIdx.x * 256 + threadIdx.x;   // total = 32*100*100*25
    int q  = t % 25;
    int r  = t / 25;
    int oy = r % PP;
    r /= PP;
    int ox = r % PP;
    int c  = r / PP;
    int oz0 = q * 4;

    // nominal source z for u[m]: oz0-3+m, m=0..5; clamped load bases
    int baseA = max(oz0 - 4, 0);
    int baseB = min(oz0, HH - 4);
    float zm[6];
#pragma unroll
    for (int m = 0; m < 6; ++m)
        zm[m] = ((unsigned)(oz0 - 3 + m) < (unsigned)HH) ? 1.0f : 0.0f;

    float u0 = 0.f, u1 = 0.f, u2 = 0.f, u3 = 0.f, u4 = 0.f, u5 = 0.f;
#pragma unroll
    for (int a = 0; a < 3; ++a) {
        int sx = ox - 3 + a;
        if ((unsigned)sx >= (unsigned)HH) continue;
#pragma unroll
        for (int b = 0; b < 3; ++b) {
            int sy = oy - 3 + b;
            if ((unsigned)sy >= (unsigned)HH) continue;
            const float* row = fix + ((size_t)((c * HH + sx) * HH + sy)) * HH;
            float4 LA = *(const float4*)(row + baseA);
            float4 LB = *(const float4*)(row + baseB);
            u0 += LA.y; u1 += LA.z; u2 += LA.w;   // nominal z oz0-3..oz0-1
            u3 += LB.x; u4 += LB.y; u5 += LB.z;   // nominal z oz0..oz0+2
        }
    }
    u0 *= zm[0]; u1 *= zm[1]; u2 *= zm[2];
    u3 *= zm[3]; u4 *= zm[4]; u5 *= zm[5];

    float4 o;
    o.x = u0 + u1 + u2;
    o.y = u1 + u2 + u3;
    o.z = u2 + u3 + u4;
    o.w = u3 + u4 + u5;
    *(float4*)(pf + ((size_t)((c * PP + ox) * PP + oy)) * PP + oz0) = o;
}

// ---------------- Stage 2: LDS-tiled correlation, 4 z/thread ----------------
__global__ __launch_bounds__(TPB) void corr3(const float* __restrict__ mov,
                                             const float* __restrict__ pf,
                                             float* __restrict__ out) {
    // xs: x-presummed mov, rows r=0..9 (sy=y0-1+r), z at zi=z+4 (pads zero)
    __shared__ float xs[(TY + 2) * MST];
    // ps: pf planes i=0..2, rows r=0..11 (py=y0+r), z at zi=oz
    __shared__ float ps[3 * (TY + 4) * MST];

    const int tid = threadIdx.x;
    const int zq  = tid % NZQ;          // 0..23
    const int yy  = tid / NZQ;          // 0..7
    const int z0  = zq * 4;

    // XCD-aware bijective swizzle: 1152 blocks = 8 XCD * 144
    const int bid = blockIdx.x;
    const int tile = (bid & 7) * 144 + (bid >> 3);
    const int bx = tile % 96;
    const int by = tile / 96;           // 0..11
    const int y0 = by * TY;

    // Pre-zero xs once: z-pads (zi<4, zi>=100) + OOB rows stay zero forever.
    for (int s = tid; s < (TY + 2) * MST; s += TPB) xs[s] = 0.f;

    float acc[27][4];
#pragma unroll
    for (int d = 0; d < 27; ++d)
#pragma unroll
        for (int qq = 0; qq < 4; ++qq) acc[d][qq] = 0.f;

    const int NXS = (TY + 2) * (HH / 4);        // 240 xs f4 slots
    const int NPS = 3 * (TY + 4) * (PP / 4);    // 900 ps f4 slots

    const bool xlo = (bx >= 1), xhi = (bx <= HH - 2);

    for (int c = 0; c < CCH; ++c) {
        __syncthreads();   // previous compute done (and initial pre-zero)
        for (int s = tid; s < NXS + NPS; s += TPB) {
            if (s < NXS) {
                int q = s % (HH / 4);
                int r = s / (HH / 4);              // 0..9
                int sy = y0 - 1 + r;
                float4 v = {0.f, 0.f, 0.f, 0.f};
                if ((unsigned)sy < (unsigned)HH) {
                    const float* base =
                        mov + ((size_t)(c * HH + bx) * HH + sy) * HH + 4 * q;
                    const size_t pstr = (size_t)HH * HH;   // x-plane stride
                    if (xlo) {
                        float4 a = *(const float4*)(base - pstr);
                        v.x += a.x; v.y += a.y; v.z += a.z; v.w += a.w;
                    }
                    {
                        float4 a = *(const float4*)(base);
                        v.x += a.x; v.y += a.y; v.z += a.z; v.w += a.w;
                    }
                    if (xhi) {
                        float4 a = *(const float4*)(base + pstr);
                        v.x += a.x; v.y += a.y; v.z += a.z; v.w += a.w;
                    }
                }
                *(float4*)(xs + r * MST + 4 + 4 * q) = v;
            } else {
                int s2 = s - NXS;
                int q  = s2 % (PP / 4);
                int rr = s2 / (PP / 4);            // 0..35
                int r  = rr % (TY + 4);
                int i  = rr / (TY + 4);
                int px = bx + 2 * i, py = y0 + r;  // always in-bounds
                float4 v = *(const float4*)(
                    pf + ((size_t)((c * PP + px) * PP + py)) * PP + 4 * q);
                *(float4*)(ps + (i * (TY + 4) + r) * MST + 4 * q) = v;
            }
        }
        __syncthreads();

        // bm[q] (q=0..3): 3 columns (b=0..2), window zi z0+3+q .. z0+5+q
        float bmv[4] = {0.f, 0.f, 0.f, 0.f};
#pragma unroll
        for (int b = 0; b < 3; ++b) {
            const float* col = xs + (yy + b) * MST + z0 + 2;  // 8B aligned
            float2 e0 = *(const float2*)(col);       // zi z0+2, z0+3
            float2 e1 = *(const float2*)(col + 2);   // z0+4, z0+5
            float2 e2 = *(const float2*)(col + 4);   // z0+6, z0+7
            float2 e3 = *(const float2*)(col + 6);   // z0+8, z0+9
            bmv[0] += e0.y + e1.x + e1.y;
            bmv[1] += e1.x + e1.y + e2.x;
            bmv[2] += e1.y + e2.x + e2.y;
            bmv[3] += e2.x + e2.y + e3.x;
        }

        // taps: aligned b128 pair per (i,j) serves 4 z x 3 k
#pragma unroll
        for (int i = 0; i < 3; ++i)
#pragma unroll
            for (int j = 0; j < 3; ++j) {
                const float* col =
                    ps + (i * (TY + 4) + (yy + 2 * j)) * MST + z0;  // 16B aligned
                float4 w0 = *(const float4*)(col);
                float4 w1 = *(const float4*)(col + 4);
                float w[8] = {w0.x, w0.y, w0.z, w0.w, w1.x, w1.y, w1.z, w1.w};
#pragma unroll
                for (int k = 0; k < 3; ++k) {
                    int d = i * 9 + j * 3 + k;
#pragma unroll
                    for (int qq = 0; qq < 4; ++qq)
                        acc[d][qq] = fmaf(bmv[qq], w[qq + 2 * k], acc[d][qq]);
                }
            }
    }

    const float sc = 1.0f / 27.0f;
    const int yo = y0 + yy;
#pragma unroll
    for (int d = 0; d < 27; ++d) {
        float4 o;
        o.x = acc[d][0] * sc;
        o.y = acc[d][1] * sc;
        o.z = acc[d][2] * sc;
        o.w = acc[d][3] * sc;
        *(float4*)(out + ((size_t)((d * HH + bx) * HH + yo)) * HH + z0) = o;
    }
}

extern "C" void kernel_launch(void* const* d_in, const int* in_sizes, int n_in,
                              void* d_out, int out_size, void* d_ws, size_t ws_size,
                              hipStream_t stream) {
    const float* mov = (const float*)d_in[0];
    const float* fix = (const float*)d_in[1];
    float* out = (float*)d_out;
    float* pf  = (float*)d_ws;

    // pf needs 32*100^3*4 = 128,000,000 bytes of workspace.
    if (ws_size < (size_t)CCH * PP * PP * PP * sizeof(float)) return;

    // Stage 1: 32*100*100*25 = 8,000,000 threads -> 31250 blocks of 256
    pf2<<<31250, 256, 0, stream>>>(fix, pf);

    // Stage 2: 1152 blocks (8 XCD * 144), 192 threads
    corr3<<<1152, TPB, 0, stream>>>(mov, pf, out);
}